// Round 9
// baseline (693.288 us; speedup 1.0000x reference)
//
#include <hip/hip_runtime.h>
#include <cstdint>

// Board: 4096 x 4096 int32 in {0,1,2}  (0=empty, 1=black, 2=white)
// Outputs BOOLEAN -> int32 (0/1), concatenated flat in d_out:
//   bamboo_b, bamboo_w, tiger_b, tiger_w, etri_b, etri_w  -> each (4095,4095)
//   eye_b, eye_w                                          -> each (4094,4094)
//
// R9: bitboard rewrite. One wave per 64-board-col band (65 bands x 63 output
// cols = 4095 exactly). Per row: each lane loads cols (c, c+1); __ballot
// gives wave-uniform 64-bit masks B/W (E = ~(B|W)). All motif planes become
// ~80 SALU bitwise ops per row for 63 cells; per-lane VALU ~26 inst/row
// (was ~430): removes the ~92 us VALU floor of the per-cell int kernels.
// Corner streams for cell (i,j): a=lo[i] bit j, b=hi[i] bit j,
// c=lo[i+1] bit j, d=hi[i+1] bit j. Eye right-arm (i+1,j+2) = hi[i+1]>>1.

#define BW 4096
#define W1 4095
#define W2 4094
#define N1 16769025ULL   // 4095*4095
#define N2 16760836ULL   // 4094*4094
#define RSTRIP 15        // 273 * 15 = 4095

__global__ __launch_bounds__(64)
void motif_kernel(const int* __restrict__ board, int* __restrict__ out) {
    const int lane = threadIdx.x;            // 0..63
    const int band = blockIdx.x;             // 0..64
    const int i0   = blockIdx.y * RSTRIP;    // 0,15,...,4080
    const int col  = band * 63 + lane;       // lo col, always <= 4095
    const int colh = (col < W1) ? col + 1 : W1;  // hi col, clamped (band 64 lane 63)

    // rolling per-row wave-uniform bitboards
    uint64_t Bl[3], Bh[3], Wl[3], Wh[3];

    auto load_row = [&](int row, int s) {
        const int* p = board + (size_t)row * BW;
        const int vlo = p[col];
        const int vhi = p[colh];
        Bl[s] = __ballot(vlo == 1);
        Wl[s] = __ballot(vlo == 2);
        Bh[s] = __ballot(vhi == 1);
        Wh[s] = __ballot(vhi == 2);
    };

    load_row(i0, 0);
    load_row(i0 + 1, 1);

    const bool cellStore = (lane < 63);          // cell col = band*63+lane <= 4094
    const bool eyeColOk  = cellStore && (col < W2);

    #pragma unroll 3
    for (int r = 0; r < RSTRIP; ++r) {
        const int i  = i0 + r;                   // output row, <= 4094
        const int s0 = r % 3, s1 = (r + 1) % 3, s2 = (r + 2) % 3;

        int rowLoad = i + 2;                     // needed only for eyes (i<4094)
        if (rowLoad > W1) rowLoad = W1;          // clamp: loaded-but-unused
        load_row(rowLoad, s2);

        // corner streams (bit j = cell at output col band*63+j)
        const uint64_t Ba = Bl[s0], Bb = Bh[s0], Bc = Bl[s1], Bd = Bh[s1];
        const uint64_t Wa = Wl[s0], Wb = Wh[s0], Wc = Wl[s1], Wd = Wh[s1];
        const uint64_t Ea = ~(Ba | Wa);
        const uint64_t Eb = ~(Bb | Wb);
        const uint64_t Ec = ~(Bc | Wc);
        const uint64_t Ed = ~(Bd | Wd);

        // bamboo: (diag==2 & empty_anti==2) | (anti==2 & empty_diag==2)
        const uint64_t bamboo_b = (Ba & Bd & Eb & Ec) | (Bb & Bc & Ea & Ed);
        const uint64_t bamboo_w = (Wa & Wd & Eb & Ec) | (Wb & Wc & Ea & Ed);

        // tiger: >=2 of 4 corners same color, and any empty corner
        const uint64_t anyE = Ea | Eb | Ec | Ed;
        const uint64_t tb2 = (Ba&Bb)|(Ba&Bc)|(Ba&Bd)|(Bb&Bc)|(Bb&Bd)|(Bc&Bd);
        const uint64_t tw2 = (Wa&Wb)|(Wa&Wc)|(Wa&Wd)|(Wb&Wc)|(Wb&Wd)|(Wc&Wd);
        const uint64_t tiger_b = tb2 & anyE;
        const uint64_t tiger_w = tw2 & anyE;

        // empty triangle: exactly 3 same color + the remaining corner empty
        const uint64_t etri_b = (Ea&Bb&Bc&Bd)|(Ba&Eb&Bc&Bd)|(Ba&Bb&Ec&Bd)|(Ba&Bb&Bc&Ed);
        const uint64_t etri_w = (Ea&Wb&Wc&Wd)|(Wa&Eb&Wc&Wd)|(Wa&Wb&Ec&Wd)|(Wa&Wb&Wc&Ed);

        // eye at (i,j): center (i+1,j+1)=Ed, up (i,j+1)=*b, left (i+1,j)=*c,
        // right (i+1,j+2)=*d>>1, down (i+2,j+1)=*h[s2]
        const uint64_t eye_b = Ed & Bb & Bc & (Bd >> 1) & Bh[s2];
        const uint64_t eye_w = Ed & Wb & Wc & (Wd >> 1) & Wh[s2];

        const size_t orow = (size_t)i * W1 + col;
        if (cellStore) {
            out[orow]            = (int)((bamboo_b >> lane) & 1);
            out[orow + N1]       = (int)((bamboo_w >> lane) & 1);
            out[orow + 2 * N1]   = (int)((tiger_b  >> lane) & 1);
            out[orow + 3 * N1]   = (int)((tiger_w  >> lane) & 1);
            out[orow + 4 * N1]   = (int)((etri_b   >> lane) & 1);
            out[orow + 5 * N1]   = (int)((etri_w   >> lane) & 1);
        }
        if (eyeColOk && (i < W2)) {
            const size_t oeye = 6 * N1 + (size_t)i * W2 + col;
            out[oeye]      = (int)((eye_b >> lane) & 1);
            out[oeye + N2] = (int)((eye_w >> lane) & 1);
        }
    }
}

extern "C" void kernel_launch(void* const* d_in, const int* in_sizes, int n_in,
                              void* d_out, int out_size, void* d_ws, size_t ws_size,
                              hipStream_t stream) {
    const int* board = (const int*)d_in[0];
    int* out = (int*)d_out;

    dim3 block(64, 1, 1);                 // one wave per block (band x strip)
    dim3 grid(65, 273, 1);                // 65 bands x (273*15 = 4095 rows)
    motif_kernel<<<grid, block, 0, stream>>>(board, out);
}

// Round 10
// 593.146 us; speedup vs baseline: 1.1688x; 1.1688x over previous
//
#include <hip/hip_runtime.h>
#include <cstdint>

// Board: 4096 x 4096 int32 in {0,1,2}  (0=empty, 1=black, 2=white)
// Outputs BOOLEAN -> int32 (0/1), concatenated flat in d_out:
//   bamboo_b, bamboo_w, tiger_b, tiger_w, etri_b, etri_w  -> each (4095,4095)
//   eye_b, eye_w                                          -> each (4094,4094)
//
// R10 = R8 memory structure (2 rows/block, phase-aligned 16B stores)
//     + SWAR bitboard compute: each thread packs its 8-col row window into a
//       16-bit reg (2-bit fields), derives strided B/W/E masks (&0x5555) and
//       evaluates all 7 cells of all 8 planes with ~65 bitwise ops
//       (vs ~7x50 scalar int ops in R8). Position+1 == >>2, position+2 == >>4.

#define BW 4096
#define W1 4095
#define W2 4094
#define N1 16769025   // 4095*4095, % 4 == 1
#define N2 16760836   // 4094*4094, % 4 == 0
#define M55 0x5555u

typedef int i4a __attribute__((vector_size(16), aligned(16)));

struct Planes { unsigned pm[6]; unsigned em[2]; };

// m0/m1/m2: packed rows i, i+1, i+2 (2-bit fields, pos k at bits 2k..2k+1)
__device__ __forceinline__ Planes compute_swar(unsigned m0, unsigned m1, unsigned m2)
{
    const unsigned B0 = m0 & M55,        W0 = (m0 >> 1) & M55;
    const unsigned B1 = m1 & M55,        Wl = (m1 >> 1) & M55;
    const unsigned B2 = m2 & M55,        W2m = (m2 >> 1) & M55;
    const unsigned E0 = (B0 | W0) ^ M55;
    const unsigned E1 = (B1 | Wl) ^ M55;

    // corner streams for cell p: a=row0 pos p, b=row0 pos p+1 (>>2),
    //                            c=row1 pos p, d=row1 pos p+1 (>>2)
    const unsigned sB0 = B0 >> 2, sB1 = B1 >> 2;
    const unsigned sW0 = W0 >> 2, sW1 = Wl >> 2;
    const unsigned sE0 = E0 >> 2, sE1 = E1 >> 2;
    const unsigned sB2 = B2 >> 2, sW2 = W2m >> 2;

    const unsigned EaEd = E0 & sE1;              // diag pair both empty
    const unsigned EbEc = sE0 & E1;              // anti pair both empty
    const unsigned anyE = E0 | sE0 | E1 | sE1;   // >=1 empty corner

    Planes r;
    {   // black
        const unsigned P = B0 & sB0, Q = B1 & sB1;     // top pair / bottom pair
        const unsigned Dg = B0 & sB1, Ag = sB0 & B1;   // diag / anti
        const unsigned X = B0 & B1,  Y = sB0 & sB1;    // columns
        const unsigned ge2 = P | Q | Dg | Ag | X | Y;          // >=2 black
        const unsigned ge3 = (P & (B1 | sB1)) | (Q & (B0 | sB0)); // >=3 black
        r.pm[0] = (Dg & EbEc) | (Ag & EaEd);   // bamboo_b
        r.pm[2] = ge2 & anyE;                  // tiger_b
        r.pm[4] = ge3 & anyE;                  // etri_b (==3 & exactly-1-empty)
        // eye: center E(r1,p+1), up B(r0,p+1), left B(r1,p), right B(r1,p+2), down B(r2,p+1)
        r.em[0] = sE1 & sB0 & B1 & (B1 >> 4) & sB2;
    }
    {   // white
        const unsigned P = W0 & sW0, Q = Wl & sW1;
        const unsigned Dg = W0 & sW1, Ag = sW0 & Wl;
        const unsigned X = W0 & Wl,  Y = sW0 & sW1;
        const unsigned ge2 = P | Q | Dg | Ag | X | Y;
        const unsigned ge3 = (P & (Wl | sW1)) | (Q & (W0 | sW0));
        r.pm[1] = (Dg & EbEc) | (Ag & EaEd);
        r.pm[3] = ge2 & anyE;
        r.pm[5] = ge3 & anyE;
        r.em[1] = sE1 & sW0 & Wl & (Wl >> 4) & sW2;
    }
    return r;
}

template<int PH>   // PH = i & 3
__device__ __forceinline__ void store_row(
    int* __restrict__ out, const int i, const int u, const bool has2,
    const Planes& pl)
{
    const bool fullv = (u < 1023);
    const size_t orow = (size_t)i * W1 + (u << 2);

    #pragma unroll
    for (int p = 0; p < 6; ++p) {
        const int sp = (PH - p) & 3;           // compile-time
        int* dst = out + (size_t)p * N1 + orow;
        if (fullv) {
            i4a s;
            s[0] = (int)((pl.pm[p] >> (2 * (sp + 0))) & 1);
            s[1] = (int)((pl.pm[p] >> (2 * (sp + 1))) & 1);
            s[2] = (int)((pl.pm[p] >> (2 * (sp + 2))) & 1);
            s[3] = (int)((pl.pm[p] >> (2 * (sp + 3))) & 1);
            *(i4a*)(dst + sp) = s;             // 16B-aligned by construction
        } else {                               // u == 1023: cols 4092+sp .. 4094
            #pragma unroll
            for (int k = 0; k < 3 - sp; ++k)
                dst[sp + k] = (int)((pl.pm[p] >> (2 * (sp + k))) & 1);
        }
        if (u == 0) {                          // head cols 0 .. sp-1
            #pragma unroll
            for (int k = 0; k < sp; ++k)
                dst[k] = (int)((pl.pm[p] >> (2 * k)) & 1);
        }
    }

    if (has2) {
        const int e = (PH & 1) ? 0 : 2;        // compile-time eye phase
        int* d0 = out + (size_t)6 * N1 + (size_t)i * W2 + (u << 2);
        int* d1 = d0 + N2;
        if (fullv) {
            i4a s0, s1;
            #pragma unroll
            for (int k = 0; k < 4; ++k) {
                s0[k] = (int)((pl.em[0] >> (2 * (e + k))) & 1);
                s1[k] = (int)((pl.em[1] >> (2 * (e + k))) & 1);
            }
            *(i4a*)(d0 + e) = s0;              // 16B-aligned by construction
            *(i4a*)(d1 + e) = s1;
        } else if (e == 0) {                   // u == 1023: cols 4092, 4093
            #pragma unroll
            for (int k = 0; k < 2; ++k) {
                d0[k] = (int)((pl.em[0] >> (2 * k)) & 1);
                d1[k] = (int)((pl.em[1] >> (2 * k)) & 1);
            }
        }
        if (u == 0) {                          // head cols 0 .. e-1
            #pragma unroll
            for (int k = 0; k < e; ++k) {
                d0[k] = (int)((pl.em[0] >> (2 * k)) & 1);
                d1[k] = (int)((pl.em[1] >> (2 * k)) & 1);
            }
        }
    }
}

template<int I0M4>   // i0 & 3: 0 or 2
__device__ __forceinline__ void strip_body(
    const int* __restrict__ board, int* __restrict__ out,
    const int u, const int i0)
{
    const int base = u << 2;
    const bool fullv = (u < 1023);
    const bool lastStrip = (i0 == W1 - 1);    // i0 == 4094: only row i0, no eyes

    // rows i0 .. i0+3 (clamped; clamped rows feed only unused outputs)
    const int rC = (i0 + 2 <= W1) ? i0 + 2 : W1;
    const int rD = (i0 + 3 <= W1) ? i0 + 3 : W1;

    // issue all loads first, pack after (overlap latency)
    const int* pA = board + (size_t)i0 * BW + base;
    const int* pB = board + (size_t)(i0 + 1) * BW + base;
    const int* pC = board + (size_t)rC * BW + base;
    const int* pD = board + (size_t)rD * BW + base;
    i4a vA = *(const i4a*)pA;
    i4a vB = *(const i4a*)pB;
    i4a vC = *(const i4a*)pC;
    i4a vD = *(const i4a*)pD;
    i4a xA = {0,0,0,0}, xB = {0,0,0,0}, xC = {0,0,0,0}, xD = {0,0,0,0};
    if (fullv) {
        xA = *(const i4a*)(pA + 4);
        xB = *(const i4a*)(pB + 4);
        xC = *(const i4a*)(pC + 4);
        xD = *(const i4a*)(pD + 4);
    }

    auto pack = [](const i4a& v, const i4a& x) -> unsigned {
        return (unsigned)(v[0] | (v[1] << 2) | (v[2] << 4) | (v[3] << 6)
                        | (x[0] << 8) | (x[1] << 10) | (x[2] << 12) | (x[3] << 14));
    };
    const unsigned m0 = pack(vA, xA);
    const unsigned m1 = pack(vB, xB);
    const unsigned m2 = pack(vC, xC);
    const unsigned m3 = pack(vD, xD);

    // output row i0 (eyes need row i0+2 -> only if !lastStrip)
    Planes P0 = compute_swar(m0, m1, m2);
    store_row<I0M4>(out, i0, u, !lastStrip, P0);

    // output row i0+1 (exists iff !lastStrip); eyes need i0+3 (valid: i0<=4092)
    if (!lastStrip) {
        Planes P1 = compute_swar(m1, m2, m3);
        store_row<(I0M4 + 1) & 3>(out, i0 + 1, u, true, P1);
    }
}

__global__ __launch_bounds__(256)
void motif_kernel(const int* __restrict__ board, int* __restrict__ out) {
    const int u  = blockIdx.x * 256 + threadIdx.x;  // 0..1023
    const int i0 = blockIdx.y << 1;                 // 0,2,...,4094

    if ((i0 & 2) == 0) strip_body<0>(board, out, u, i0);
    else               strip_body<2>(board, out, u, i0);
}

extern "C" void kernel_launch(void* const* d_in, const int* in_sizes, int n_in,
                              void* d_out, int out_size, void* d_ws, size_t ws_size,
                              hipStream_t stream) {
    const int* board = (const int*)d_in[0];
    int* out = (int*)d_out;

    dim3 block(256, 1, 1);
    dim3 grid(4, 2048, 1);   // 2 output rows per block (last block: 1 row)
    motif_kernel<<<grid, block, 0, stream>>>(board, out);
}